// Round 1
// baseline (333.313 us; speedup 1.0000x reference)
//
#include <hip/hip_runtime.h>
#include <stdint.h>

#define NNODES 100000
#define NEDGES 1000000
#define DIM 64
#define NRELS 16
#define EPB 2048
#define NB ((NEDGES + EPB - 1) / EPB)   /* 489 */
#define PADCAP (NEDGES + NRELS * 64)    /* 1001024 */
#define MAXTILES (PADCAP / 64)          /* 15641 */

// ws layout (bytes):
//   featB  @ 0          : ushort[NNODES*64]   = 12,800,000
//   Wt     @ 12800000   : ushort[16*64*64]    = 131,072
//   hist   @ 12931072   : int[NB*16]          (reserve 32768)
//   bbase  @ 12963840   : int[NB*16]          (reserve 32768)
//   Pve    @ 12996608   : int[33]             (P[0..16], validEnd[0..15])
//   srcS   @ 12996864   : int[PADCAP]         = 4,004,096
//   dstS   @ 17000960   : int[PADCAP]         = 4,004,096  (end ~21 MB)

using short8  = __attribute__((ext_vector_type(8))) short;
using floatx4 = __attribute__((ext_vector_type(4))) float;

__device__ __forceinline__ unsigned short f2bf(float f) {
    union { float f; uint32_t u; } v; v.f = f;
    uint32_t u = v.u;
    return (unsigned short)((u + 0x7FFFu + ((u >> 16) & 1u)) >> 16);
}

__global__ void k_convert_feat(const float* __restrict__ feat,
                               unsigned short* __restrict__ featB) {
    int i = (blockIdx.x * blockDim.x + threadIdx.x) * 4; // exactly covers 6.4e6
    const float4 f = *(const float4*)(feat + i);
    ushort4 o;
    o.x = f2bf(f.x); o.y = f2bf(f.y); o.z = f2bf(f.z); o.w = f2bf(f.w);
    *(ushort4*)(featB + i) = o;
}

// Wt[r][n][k] = bf16(W[r][k][n])  -- transposed so B-frag loads are contiguous
__global__ void k_convert_w(const float* __restrict__ W,
                            unsigned short* __restrict__ Wt) {
    int t = blockIdx.x * blockDim.x + threadIdx.x; // 65536
    int r = t >> 12, n = (t >> 6) & 63, k = t & 63;
    Wt[t] = f2bf(W[(r << 12) + (k << 6) + n]);
}

__global__ void k_hist(const int* __restrict__ et, int* __restrict__ hist) {
    __shared__ int cnt[16];
    if (threadIdx.x < 16) cnt[threadIdx.x] = 0;
    __syncthreads();
    int start = blockIdx.x * EPB;
    int end = min(NEDGES, start + EPB);
    for (int i = start + threadIdx.x; i < end; i += 256)
        atomicAdd(&cnt[et[i]], 1);
    __syncthreads();
    if (threadIdx.x < 16) hist[blockIdx.x * 16 + threadIdx.x] = cnt[threadIdx.x];
}

// one block, 1024 threads = 16 waves; wave w scans relation w across NB blocks
__global__ void k_scan(const int* __restrict__ hist, int* __restrict__ bbase,
                       int* __restrict__ Pve) {
    __shared__ int s_cnt[16];
    __shared__ int s_P[17];
    int w = threadIdx.x >> 6;
    int lane = threadIdx.x & 63;
    int carry = 0;
    for (int c = 0; c < NB; c += 64) {
        int idx = c + lane;
        int v = (idx < NB) ? hist[idx * 16 + w] : 0;
        int x = v;
        #pragma unroll
        for (int off = 1; off < 64; off <<= 1) {
            int y = __shfl_up(x, off);
            if (lane >= off) x += y;
        }
        if (idx < NB) bbase[idx * 16 + w] = carry + x - v; // exclusive, no P yet
        carry += __shfl(x, 63);
    }
    if (lane == 0) s_cnt[w] = carry;
    __syncthreads();
    if (threadIdx.x == 0) {
        int p = 0;
        for (int r = 0; r < 16; ++r) {
            s_P[r] = p;
            Pve[r] = p;
            Pve[17 + r] = p + s_cnt[r];       // validEnd[r]
            p += (s_cnt[r] + 63) & ~63;       // pad bucket to multiple of 64
        }
        s_P[16] = p;
        Pve[16] = p;
    }
    __syncthreads();
    int pw = s_P[w];
    for (int idx = lane; idx < NB; idx += 64)
        bbase[idx * 16 + w] += pw;
}

__global__ void k_scatter(const int* __restrict__ et, const int* __restrict__ src,
                          const int* __restrict__ dst, const int* __restrict__ bbase,
                          int* __restrict__ srcS, int* __restrict__ dstS) {
    __shared__ int base[16];
    if (threadIdx.x < 16) base[threadIdx.x] = bbase[blockIdx.x * 16 + threadIdx.x];
    __syncthreads();
    int start = blockIdx.x * EPB;
    int end = min(NEDGES, start + EPB);
    for (int i = start + threadIdx.x; i < end; i += 256) {
        int r = et[i];
        int pos = atomicAdd(&base[r], 1);
        srcS[pos] = src[i];
        dstS[pos] = dst[i];
    }
}

// one wave per 64-edge tile (single relation per tile by construction)
__global__ void __launch_bounds__(256)
k_compute(const unsigned short* __restrict__ featB,
          const unsigned short* __restrict__ Wt,
          const int* __restrict__ srcS, const int* __restrict__ dstS,
          const int* __restrict__ Pve, float* __restrict__ out) {
    const int t = blockIdx.x * 4 + (threadIdx.x >> 6);
    const int base = t * 64;
    const int total = Pve[16];
    if (base >= total) return;
    int r = 0;
    while (base >= Pve[r + 1]) ++r;
    const int validEnd = Pve[17 + r];
    const int lane = threadIdx.x & 63;
    const int quad = lane >> 4;
    const int l16 = lane & 15;

    // B fragments: Wt[r][n][k], lane holds n = tn*16+l16, k = ks*32 + quad*8 .. +8
    const unsigned short* wr = Wt + (r << 12);
    short8 bfr[4][2];
    #pragma unroll
    for (int tn = 0; tn < 4; ++tn)
        #pragma unroll
        for (int ks = 0; ks < 2; ++ks)
            bfr[tn][ks] = *(const short8*)(wr + ((tn * 16 + l16) << 6) + ks * 32 + quad * 8);

    #pragma unroll
    for (int tm = 0; tm < 4; ++tm) {
        int row = base + tm * 16 + l16;
        int s = (row < validEnd) ? srcS[row] : 0;
        const unsigned short* fp = featB + (s << 6) + quad * 8;
        short8 a0 = *(const short8*)(fp);        // k = quad*8 .. +8
        short8 a1 = *(const short8*)(fp + 32);   // k = 32 + quad*8 .. +8
        floatx4 cc[4];
        #pragma unroll
        for (int tn = 0; tn < 4; ++tn) {
            floatx4 c = {0.f, 0.f, 0.f, 0.f};
            c = __builtin_amdgcn_mfma_f32_16x16x32_bf16(a0, bfr[tn][0], c, 0, 0, 0);
            c = __builtin_amdgcn_mfma_f32_16x16x32_bf16(a1, bfr[tn][1], c, 0, 0, 0);
            cc[tn] = c;
        }
        // C layout: col = l16, row = quad*4 + j
        int pos0 = base + tm * 16 + quad * 4;
        const int4 d4 = *(const int4*)(dstS + pos0);
        #pragma unroll
        for (int j = 0; j < 4; ++j) {
            if (pos0 + j < validEnd) {
                int dn = (j == 0 ? d4.x : j == 1 ? d4.y : j == 2 ? d4.z : d4.w);
                float* op = out + (dn << 6) + l16;
                #pragma unroll
                for (int tn = 0; tn < 4; ++tn)
                    atomicAdd(op + tn * 16, cc[tn][j]);
            }
        }
    }
}

extern "C" void kernel_launch(void* const* d_in, const int* in_sizes, int n_in,
                              void* d_out, int out_size, void* d_ws, size_t ws_size,
                              hipStream_t stream) {
    const float* feat = (const float*)d_in[0];
    const float* W    = (const float*)d_in[1];
    const int* src    = (const int*)d_in[2];
    const int* dst    = (const int*)d_in[3];
    const int* et     = (const int*)d_in[4];
    float* out = (float*)d_out;
    char* ws = (char*)d_ws;

    unsigned short* featB = (unsigned short*)(ws);
    unsigned short* Wt    = (unsigned short*)(ws + 12800000);
    int* hist  = (int*)(ws + 12931072);
    int* bbase = (int*)(ws + 12963840);
    int* Pve   = (int*)(ws + 12996608);
    int* srcS  = (int*)(ws + 12996864);
    int* dstS  = (int*)(ws + 17000960);

    hipMemsetAsync(d_out, 0, (size_t)out_size * sizeof(float), stream);
    k_convert_feat<<<6250, 256, 0, stream>>>(feat, featB);
    k_convert_w<<<256, 256, 0, stream>>>(W, Wt);
    k_hist<<<NB, 256, 0, stream>>>(et, hist);
    k_scan<<<1, 1024, 0, stream>>>(hist, bbase, Pve);
    k_scatter<<<NB, 256, 0, stream>>>(et, src, dst, bbase, srcS, dstS);
    k_compute<<<(MAXTILES + 3) / 4, 256, 0, stream>>>(featB, Wt, srcS, dstS, Pve, out);
}

// Round 2
// 321.228 us; speedup vs baseline: 1.0376x; 1.0376x over previous
//
#include <hip/hip_runtime.h>
#include <hip/hip_bf16.h>
#include <stdint.h>

#define NNODES 100000
#define NEDGES 1000000
#define DIM 64
#define NRELS 16
#define EPB 2048
#define NB ((NEDGES + EPB - 1) / EPB)   /* 489 */
#define PADCAP (NEDGES + NRELS * 64)    /* 1001024 */
#define MAXTILES (PADCAP / 64)          /* 15641 */
#define NDN NNODES
#define DCH 1024
#define NCHUNK ((NDN + DCH - 1) / DCH)  /* 98 */

// ws layout (bytes):
//   featB  @ 0          : ushort[NNODES*64]   = 12,800,000
//   Wt     @ 12800000   : ushort[16*64*64]    = 131,072
//   hist   @ 12931072   : int[NB*16]          (reserve 32768)
//   bbase  @ 12963840   : int[NB*16]          (reserve 32768)
//   Pve    @ 12996608   : int[33]             (reserve 256)
//   srcS   @ 12996864   : int[PADCAP]         = 4,004,096
//   dstS   @ 17000960   : int[PADCAP]         = 4,004,096   (fallback only)
//   dhist  @ 21005056   : int[NDN]            (reserve 400,128)
//   dbase  @ 21405184   : int[NDN]            (reserve 400,128)
//   csum   @ 21805312   : int[NCHUNK]         (reserve 512)
//   eperm  @ 21805824   : int[NEDGES]         = 4,000,000
//   msgE   @ 25805824   : ushort[PADCAP*64]   = 128,131,072  -> end 153,936,896
#define WS_NEED 153936896ull

using short8  = __attribute__((ext_vector_type(8))) short;
using floatx4 = __attribute__((ext_vector_type(4))) float;

__device__ __forceinline__ unsigned short f2bf(float f) {
    union { float f; uint32_t u; } v; v.f = f;
    uint32_t u = v.u;
    return (unsigned short)((u + 0x7FFFu + ((u >> 16) & 1u)) >> 16);
}
__device__ __forceinline__ float bf2f(unsigned short u) {
    union { uint32_t u; float f; } v; v.u = ((uint32_t)u) << 16;
    return v.f;
}
__device__ __forceinline__ uint32_t pk2(float a, float b) {
    __hip_bfloat162 h = __float22bfloat162_rn(make_float2(a, b));
    union { __hip_bfloat162 h; uint32_t u; } v; v.h = h;
    return v.u;
}

__global__ void k_convert_feat(const float* __restrict__ feat,
                               unsigned short* __restrict__ featB) {
    int i = (blockIdx.x * blockDim.x + threadIdx.x) * 4;
    const float4 f = *(const float4*)(feat + i);
    ushort4 o;
    o.x = f2bf(f.x); o.y = f2bf(f.y); o.z = f2bf(f.z); o.w = f2bf(f.w);
    *(ushort4*)(featB + i) = o;
}

// Wt[r][n][k] = bf16(W[r][k][n])
__global__ void k_convert_w(const float* __restrict__ W,
                            unsigned short* __restrict__ Wt) {
    int t = blockIdx.x * blockDim.x + threadIdx.x;
    int r = t >> 12, n = (t >> 6) & 63, k = t & 63;
    Wt[t] = f2bf(W[(r << 12) + (k << 6) + n]);
}

__global__ void k_hist(const int* __restrict__ et, int* __restrict__ hist) {
    __shared__ int cnt[16];
    if (threadIdx.x < 16) cnt[threadIdx.x] = 0;
    __syncthreads();
    int start = blockIdx.x * EPB;
    int end = min(NEDGES, start + EPB);
    for (int i = start + threadIdx.x; i < end; i += 256)
        atomicAdd(&cnt[et[i]], 1);
    __syncthreads();
    if (threadIdx.x < 16) hist[blockIdx.x * 16 + threadIdx.x] = cnt[threadIdx.x];
}

__global__ void k_scan(const int* __restrict__ hist, int* __restrict__ bbase,
                       int* __restrict__ Pve) {
    __shared__ int s_cnt[16];
    __shared__ int s_P[17];
    int w = threadIdx.x >> 6;
    int lane = threadIdx.x & 63;
    int carry = 0;
    for (int c = 0; c < NB; c += 64) {
        int idx = c + lane;
        int v = (idx < NB) ? hist[idx * 16 + w] : 0;
        int x = v;
        #pragma unroll
        for (int off = 1; off < 64; off <<= 1) {
            int y = __shfl_up(x, off);
            if (lane >= off) x += y;
        }
        if (idx < NB) bbase[idx * 16 + w] = carry + x - v;
        carry += __shfl(x, 63);
    }
    if (lane == 0) s_cnt[w] = carry;
    __syncthreads();
    if (threadIdx.x == 0) {
        int p = 0;
        for (int r = 0; r < 16; ++r) {
            s_P[r] = p;
            Pve[r] = p;
            Pve[17 + r] = p + s_cnt[r];
            p += (s_cnt[r] + 63) & ~63;
        }
        s_P[16] = p;
        Pve[16] = p;
    }
    __syncthreads();
    int pw = s_P[w];
    for (int idx = lane; idx < NB; idx += 64)
        bbase[idx * 16 + w] += pw;
}

__global__ void k_dhist(const int* __restrict__ dst, int* __restrict__ dhist) {
    int i = blockIdx.x * 256 + threadIdx.x;
    if (i < NEDGES) atomicAdd(&dhist[dst[i]], 1);
}

// per-chunk exclusive scan (1024/block) + chunk totals
__global__ void k_dscanA(const int* __restrict__ dhist, int* __restrict__ dbase,
                         int* __restrict__ csum) {
    __shared__ int wsum[16];
    __shared__ int woff[16];
    int t = threadIdx.x;
    int i = blockIdx.x * DCH + t;
    int v = (i < NDN) ? dhist[i] : 0;
    int lane = t & 63, wv = t >> 6;
    int x = v;
    #pragma unroll
    for (int off = 1; off < 64; off <<= 1) {
        int y = __shfl_up(x, off);
        if (lane >= off) x += y;
    }
    if (lane == 63) wsum[wv] = x;
    __syncthreads();
    if (wv == 0) {
        int s = (lane < 16) ? wsum[lane] : 0;
        #pragma unroll
        for (int off = 1; off < 16; off <<= 1) {
            int y = __shfl_up(s, off);
            if (lane >= off) s += y;
        }
        if (lane < 16) woff[lane] = s - wsum[lane];
        if (lane == 15) csum[blockIdx.x] = s;
    }
    __syncthreads();
    if (i < NDN) dbase[i] = woff[wv] + x - v;
}

// add cross-chunk offsets
__global__ void k_dscanB(int* __restrict__ dbase, const int* __restrict__ csum) {
    __shared__ int soff;
    int b = blockIdx.x, t = threadIdx.x;
    if (t < 64) {
        int s = ((t < b) ? csum[t] : 0) + ((t + 64 < b) ? csum[t + 64] : 0);
        #pragma unroll
        for (int off = 32; off >= 1; off >>= 1) s += __shfl_down(s, off);
        if (t == 0) soff = s;
    }
    __syncthreads();
    int i = b * DCH + t;
    if (i < NDN) dbase[i] += soff;
}

__global__ void k_scatter(const int* __restrict__ et, const int* __restrict__ src,
                          const int* __restrict__ dst, const int* __restrict__ bbase,
                          int* __restrict__ srcS, int* __restrict__ dstS,
                          int* __restrict__ dbase, int* __restrict__ eperm,
                          int buildPerm) {
    __shared__ int base[16];
    if (threadIdx.x < 16) base[threadIdx.x] = bbase[blockIdx.x * 16 + threadIdx.x];
    __syncthreads();
    int start = blockIdx.x * EPB;
    int end = min(NEDGES, start + EPB);
    for (int i = start + threadIdx.x; i < end; i += 256) {
        int r = et[i];
        int pos = atomicAdd(&base[r], 1);
        srcS[pos] = src[i];
        if (buildPerm) {
            int p = atomicAdd(&dbase[dst[i]], 1);   // dbase[n] becomes segment END
            eperm[p] = pos;
        } else {
            dstS[pos] = dst[i];
        }
    }
}

// Phase A: per 64-edge tile (single relation), GEMM -> bf16 msg rows (coalesced)
__global__ void __launch_bounds__(256)
k_computeA(const unsigned short* __restrict__ featB,
           const unsigned short* __restrict__ Wt,
           const int* __restrict__ srcS, const int* __restrict__ Pve,
           unsigned short* __restrict__ msgE) {
    __shared__ float lds[4][16 * 68];   // per-wave 16x64 transpose, stride 68 (2-way only)
    const int w = threadIdx.x >> 6;
    const int t = blockIdx.x * 4 + w;
    const int base = t * 64;
    const int total = Pve[16];
    if (base >= total) return;
    int r = 0;
    while (base >= Pve[r + 1]) ++r;
    const int validEnd = Pve[17 + r];
    const int lane = threadIdx.x & 63;
    const int quad = lane >> 4;
    const int l16 = lane & 15;

    const unsigned short* wr = Wt + (r << 12);
    short8 bfr[4][2];
    #pragma unroll
    for (int tn = 0; tn < 4; ++tn)
        #pragma unroll
        for (int ks = 0; ks < 2; ++ks)
            bfr[tn][ks] = *(const short8*)(wr + ((tn * 16 + l16) << 6) + ks * 32 + quad * 8);

    const int rr = lane >> 2, seg = lane & 3;
    #pragma unroll
    for (int tm = 0; tm < 4; ++tm) {
        int row = base + tm * 16 + l16;
        int s = (row < validEnd) ? srcS[row] : 0;
        const unsigned short* fp = featB + (s << 6) + quad * 8;
        short8 a0 = *(const short8*)(fp);
        short8 a1 = *(const short8*)(fp + 32);
        #pragma unroll
        for (int tn = 0; tn < 4; ++tn) {
            floatx4 c = {0.f, 0.f, 0.f, 0.f};
            c = __builtin_amdgcn_mfma_f32_16x16x32_bf16(a0, bfr[tn][0], c, 0, 0, 0);
            c = __builtin_amdgcn_mfma_f32_16x16x32_bf16(a1, bfr[tn][1], c, 0, 0, 0);
            #pragma unroll
            for (int j = 0; j < 4; ++j)
                lds[w][(quad * 4 + j) * 68 + tn * 16 + l16] = c[j];
        }
        // wave-internal transpose readback: lane l -> row (l>>2), 16-col segment (l&3)
        int grow = base + tm * 16 + rr;
        if (grow < validEnd) {
            const float* lp = &lds[w][rr * 68 + seg * 16];
            uint4 o0, o1;
            o0.x = pk2(lp[0],  lp[1]);  o0.y = pk2(lp[2],  lp[3]);
            o0.z = pk2(lp[4],  lp[5]);  o0.w = pk2(lp[6],  lp[7]);
            o1.x = pk2(lp[8],  lp[9]);  o1.y = pk2(lp[10], lp[11]);
            o1.z = pk2(lp[12], lp[13]); o1.w = pk2(lp[14], lp[15]);
            uint32_t* op = (uint32_t*)(msgE + (size_t)grow * 64 + seg * 16);
            *(uint4*)(op)     = o0;
            *(uint4*)(op + 4) = o1;
        }
    }
}

// Phase B: one wave per dst node, fp32 register accumulate, no atomics
__global__ void __launch_bounds__(256)
k_reduce(const unsigned short* __restrict__ msgE, const int* __restrict__ eperm,
         const int* __restrict__ dbase, float* __restrict__ out) {
    int n = blockIdx.x * 4 + (threadIdx.x >> 6);
    if (n >= NDN) return;
    int lane = threadIdx.x & 63;
    int end = dbase[n];                 // post-scatter: segment end
    int start = n ? dbase[n - 1] : 0;
    float acc = 0.f;
    for (int bse = start; bse < end; bse += 64) {
        int cnt = min(64, end - bse);
        int idx = (lane < cnt) ? eperm[bse + lane] : 0;
        for (int j = 0; j < cnt; ++j) {
            int row = __shfl(idx, j);
            acc += bf2f(msgE[(size_t)row * 64 + lane]);
        }
    }
    out[(size_t)n * 64 + lane] = acc;
}

// Fallback: atomic epilogue (proven R1 path)
__global__ void __launch_bounds__(256)
k_compute(const unsigned short* __restrict__ featB,
          const unsigned short* __restrict__ Wt,
          const int* __restrict__ srcS, const int* __restrict__ dstS,
          const int* __restrict__ Pve, float* __restrict__ out) {
    const int t = blockIdx.x * 4 + (threadIdx.x >> 6);
    const int base = t * 64;
    const int total = Pve[16];
    if (base >= total) return;
    int r = 0;
    while (base >= Pve[r + 1]) ++r;
    const int validEnd = Pve[17 + r];
    const int lane = threadIdx.x & 63;
    const int quad = lane >> 4;
    const int l16 = lane & 15;

    const unsigned short* wr = Wt + (r << 12);
    short8 bfr[4][2];
    #pragma unroll
    for (int tn = 0; tn < 4; ++tn)
        #pragma unroll
        for (int ks = 0; ks < 2; ++ks)
            bfr[tn][ks] = *(const short8*)(wr + ((tn * 16 + l16) << 6) + ks * 32 + quad * 8);

    #pragma unroll
    for (int tm = 0; tm < 4; ++tm) {
        int row = base + tm * 16 + l16;
        int s = (row < validEnd) ? srcS[row] : 0;
        const unsigned short* fp = featB + (s << 6) + quad * 8;
        short8 a0 = *(const short8*)(fp);
        short8 a1 = *(const short8*)(fp + 32);
        floatx4 cc[4];
        #pragma unroll
        for (int tn = 0; tn < 4; ++tn) {
            floatx4 c = {0.f, 0.f, 0.f, 0.f};
            c = __builtin_amdgcn_mfma_f32_16x16x32_bf16(a0, bfr[tn][0], c, 0, 0, 0);
            c = __builtin_amdgcn_mfma_f32_16x16x32_bf16(a1, bfr[tn][1], c, 0, 0, 0);
            cc[tn] = c;
        }
        int pos0 = base + tm * 16 + quad * 4;
        const int4 d4 = *(const int4*)(dstS + pos0);
        #pragma unroll
        for (int j = 0; j < 4; ++j) {
            if (pos0 + j < validEnd) {
                int dn = (j == 0 ? d4.x : j == 1 ? d4.y : j == 2 ? d4.z : d4.w);
                float* op = out + (dn << 6) + l16;
                #pragma unroll
                for (int tn = 0; tn < 4; ++tn)
                    atomicAdd(op + tn * 16, cc[tn][j]);
            }
        }
    }
}

extern "C" void kernel_launch(void* const* d_in, const int* in_sizes, int n_in,
                              void* d_out, int out_size, void* d_ws, size_t ws_size,
                              hipStream_t stream) {
    const float* feat = (const float*)d_in[0];
    const float* W    = (const float*)d_in[1];
    const int* src    = (const int*)d_in[2];
    const int* dst    = (const int*)d_in[3];
    const int* et     = (const int*)d_in[4];
    float* out = (float*)d_out;
    char* ws = (char*)d_ws;

    unsigned short* featB = (unsigned short*)(ws);
    unsigned short* Wt    = (unsigned short*)(ws + 12800000);
    int* hist  = (int*)(ws + 12931072);
    int* bbase = (int*)(ws + 12963840);
    int* Pve   = (int*)(ws + 12996608);
    int* srcS  = (int*)(ws + 12996864);
    int* dstS  = (int*)(ws + 17000960);
    int* dhist = (int*)(ws + 21005056);
    int* dbase = (int*)(ws + 21405184);
    int* csum  = (int*)(ws + 21805312);
    int* eperm = (int*)(ws + 21805824);
    unsigned short* msgE = (unsigned short*)(ws + 25805824);

    const int usePhases = (ws_size >= WS_NEED) ? 1 : 0;

    k_convert_feat<<<6250, 256, 0, stream>>>(feat, featB);
    k_convert_w<<<256, 256, 0, stream>>>(W, Wt);
    k_hist<<<NB, 256, 0, stream>>>(et, hist);
    k_scan<<<1, 1024, 0, stream>>>(hist, bbase, Pve);

    if (usePhases) {
        hipMemsetAsync(dhist, 0, NDN * sizeof(int), stream);
        k_dhist<<<(NEDGES + 255) / 256, 256, 0, stream>>>(dst, dhist);
        k_dscanA<<<NCHUNK, DCH, 0, stream>>>(dhist, dbase, csum);
        k_dscanB<<<NCHUNK, DCH, 0, stream>>>(dbase, csum);
        k_scatter<<<NB, 256, 0, stream>>>(et, src, dst, bbase, srcS, dstS,
                                          dbase, eperm, 1);
        k_computeA<<<(MAXTILES + 3) / 4, 256, 0, stream>>>(featB, Wt, srcS, Pve, msgE);
        k_reduce<<<(NDN + 3) / 4, 256, 0, stream>>>(msgE, eperm, dbase, out);
    } else {
        hipMemsetAsync(d_out, 0, (size_t)out_size * sizeof(float), stream);
        k_scatter<<<NB, 256, 0, stream>>>(et, src, dst, bbase, srcS, dstS,
                                          dbase, eperm, 0);
        k_compute<<<(MAXTILES + 3) / 4, 256, 0, stream>>>(featB, Wt, srcS, dstS, Pve, out);
    }
}

// Round 3
// 275.085 us; speedup vs baseline: 1.2117x; 1.1677x over previous
//
#include <hip/hip_runtime.h>
#include <hip/hip_bf16.h>
#include <stdint.h>

#define NNODES 100000
#define NEDGES 1000000
#define DIM 64
#define NRELS 16
#define EPB 2048
#define NB ((NEDGES + EPB - 1) / EPB)   /* 489 */
#define PADCAP (NEDGES + NRELS * 64)    /* 1001024 */
#define MAXTILES (PADCAP / 64)          /* 15641 */
#define NDN NNODES
#define DCH 1024
#define NCHUNK ((NDN + DCH - 1) / DCH)  /* 98 */

// ws layout (bytes):
//   featB  @ 0          : ushort[NNODES*64]   = 12,800,000
//   Wt     @ 12800000   : ushort[16*64*64]    -> 12,931,072
//   hist   @ 12931072   : int[NB*16]          -> 12,963,840
//   bbase  @ 12963840   : int[NB*16]          -> 12,996,608
//   Pve    @ 12996608   : int[33]             -> 12,996,864
//   dhist  @ 12996864   : int[NDN]            -> 13,396,992
//   dbase  @ 13396992   : int[NDN]            -> 13,797,120
//   csum   @ 13797120   : int[NCHUNK]         -> 13,797,632
//   pairS  @ 13797632   : int2[PADCAP]        -> 21,805,824   {src, dstpos|dst}
//   msgE   @ 21805824   : ushort[NEDGES*64]   -> 149,805,824
#define WS_NEED 149805824ull

using short8  = __attribute__((ext_vector_type(8))) short;
using floatx4 = __attribute__((ext_vector_type(4))) float;

__device__ __forceinline__ unsigned short f2bf(float f) {
    union { float f; uint32_t u; } v; v.f = f;
    uint32_t u = v.u;
    return (unsigned short)((u + 0x7FFFu + ((u >> 16) & 1u)) >> 16);
}
__device__ __forceinline__ float bf2f(uint32_t u16) {
    union { uint32_t u; float f; } v; v.u = u16 << 16;
    return v.f;
}
__device__ __forceinline__ uint32_t pk2(float a, float b) {
    __hip_bfloat162 h = __float22bfloat162_rn(make_float2(a, b));
    union { __hip_bfloat162 h; uint32_t u; } v; v.h = h;
    return v.u;
}

__global__ void k_convert_feat(const float* __restrict__ feat,
                               unsigned short* __restrict__ featB) {
    int i = (blockIdx.x * blockDim.x + threadIdx.x) * 4;
    const float4 f = *(const float4*)(feat + i);
    ushort4 o;
    o.x = f2bf(f.x); o.y = f2bf(f.y); o.z = f2bf(f.z); o.w = f2bf(f.w);
    *(ushort4*)(featB + i) = o;
}

// Wt[r][n][k] = bf16(W[r][k][n])
__global__ void k_convert_w(const float* __restrict__ W,
                            unsigned short* __restrict__ Wt) {
    int t = blockIdx.x * blockDim.x + threadIdx.x;
    int r = t >> 12, n = (t >> 6) & 63, k = t & 63;
    Wt[t] = f2bf(W[(r << 12) + (k << 6) + n]);
}

// fused: per-block relation hist + global dst hist
__global__ void k_hist(const int* __restrict__ et, const int* __restrict__ dst,
                       int* __restrict__ hist, int* __restrict__ dhist) {
    __shared__ int cnt[16];
    if (threadIdx.x < 16) cnt[threadIdx.x] = 0;
    __syncthreads();
    int start = blockIdx.x * EPB;
    int end = min(NEDGES, start + EPB);
    for (int i = start + threadIdx.x; i < end; i += 256) {
        atomicAdd(&cnt[et[i]], 1);
        atomicAdd(&dhist[dst[i]], 1);
    }
    __syncthreads();
    if (threadIdx.x < 16) hist[blockIdx.x * 16 + threadIdx.x] = cnt[threadIdx.x];
}

__global__ void k_scan(const int* __restrict__ hist, int* __restrict__ bbase,
                       int* __restrict__ Pve) {
    __shared__ int s_cnt[16];
    __shared__ int s_P[17];
    int w = threadIdx.x >> 6;
    int lane = threadIdx.x & 63;
    int carry = 0;
    for (int c = 0; c < NB; c += 64) {
        int idx = c + lane;
        int v = (idx < NB) ? hist[idx * 16 + w] : 0;
        int x = v;
        #pragma unroll
        for (int off = 1; off < 64; off <<= 1) {
            int y = __shfl_up(x, off);
            if (lane >= off) x += y;
        }
        if (idx < NB) bbase[idx * 16 + w] = carry + x - v;
        carry += __shfl(x, 63);
    }
    if (lane == 0) s_cnt[w] = carry;
    __syncthreads();
    if (threadIdx.x == 0) {
        int p = 0;
        for (int r = 0; r < 16; ++r) {
            s_P[r] = p;
            Pve[r] = p;
            Pve[17 + r] = p + s_cnt[r];
            p += (s_cnt[r] + 63) & ~63;
        }
        s_P[16] = p;
        Pve[16] = p;
    }
    __syncthreads();
    int pw = s_P[w];
    for (int idx = lane; idx < NB; idx += 64)
        bbase[idx * 16 + w] += pw;
}

// per-chunk exclusive scan (1024/block) + chunk totals
__global__ void k_dscanA(const int* __restrict__ dhist, int* __restrict__ dbase,
                         int* __restrict__ csum) {
    __shared__ int wsum[16];
    __shared__ int woff[16];
    int t = threadIdx.x;
    int i = blockIdx.x * DCH + t;
    int v = (i < NDN) ? dhist[i] : 0;
    int lane = t & 63, wv = t >> 6;
    int x = v;
    #pragma unroll
    for (int off = 1; off < 64; off <<= 1) {
        int y = __shfl_up(x, off);
        if (lane >= off) x += y;
    }
    if (lane == 63) wsum[wv] = x;
    __syncthreads();
    if (wv == 0) {
        int s = (lane < 16) ? wsum[lane] : 0;
        #pragma unroll
        for (int off = 1; off < 16; off <<= 1) {
            int y = __shfl_up(s, off);
            if (lane >= off) s += y;
        }
        if (lane < 16) woff[lane] = s - wsum[lane];
        if (lane == 15) csum[blockIdx.x] = s;
    }
    __syncthreads();
    if (i < NDN) dbase[i] = woff[wv] + x - v;
}

__global__ void k_dscanB(int* __restrict__ dbase, const int* __restrict__ csum) {
    __shared__ int soff;
    int b = blockIdx.x, t = threadIdx.x;
    if (t < 64) {
        int s = ((t < b) ? csum[t] : 0) + ((t + 64 < b) ? csum[t + 64] : 0);
        #pragma unroll
        for (int off = 32; off >= 1; off >>= 1) s += __shfl_down(s, off);
        if (t == 0) soff = s;
    }
    __syncthreads();
    int i = b * DCH + t;
    if (i < NDN) dbase[i] += soff;
}

// pairS[pos] = {src, dstpos} (phases) or {src, dst} (fallback).
// All writes land at semi-sequential `pos` — no random-address scatter.
__global__ void k_scatter(const int* __restrict__ et, const int* __restrict__ src,
                          const int* __restrict__ dst, const int* __restrict__ bbase,
                          int* __restrict__ dbase, int2* __restrict__ pairS,
                          int buildPos) {
    __shared__ int base[16];
    if (threadIdx.x < 16) base[threadIdx.x] = bbase[blockIdx.x * 16 + threadIdx.x];
    __syncthreads();
    int start = blockIdx.x * EPB;
    int end = min(NEDGES, start + EPB);
    for (int i = start + threadIdx.x; i < end; i += 256) {
        int r = et[i];
        int pos = atomicAdd(&base[r], 1);
        int d = dst[i];
        int second = buildPos ? atomicAdd(&dbase[d], 1) : d;  // dbase -> segment END
        pairS[pos] = make_int2(src[i], second);
    }
}

// Phase A: per 64-edge tile (single relation), GEMM -> bf16 msg row at dstpos
__global__ void __launch_bounds__(256)
k_computeA(const unsigned short* __restrict__ featB,
           const unsigned short* __restrict__ Wt,
           const int2* __restrict__ pairS, const int* __restrict__ Pve,
           unsigned short* __restrict__ msgE) {
    __shared__ float lds[4][16 * 68];   // per-wave 16x64 transpose, stride 68
    const int w = threadIdx.x >> 6;
    const int t = blockIdx.x * 4 + w;
    const int base = t * 64;
    const int total = Pve[16];
    if (base >= total) return;
    int r = 0;
    while (base >= Pve[r + 1]) ++r;
    const int validEnd = Pve[17 + r];
    const int lane = threadIdx.x & 63;
    const int quad = lane >> 4;
    const int l16 = lane & 15;

    const unsigned short* wr = Wt + (r << 12);
    short8 bfr[4][2];
    #pragma unroll
    for (int tn = 0; tn < 4; ++tn)
        #pragma unroll
        for (int ks = 0; ks < 2; ++ks)
            bfr[tn][ks] = *(const short8*)(wr + ((tn * 16 + l16) << 6) + ks * 32 + quad * 8);

    const int rr = lane >> 2, seg = lane & 3;
    #pragma unroll
    for (int tm = 0; tm < 4; ++tm) {
        int row = base + tm * 16 + l16;
        int s = (row < validEnd) ? pairS[row].x : 0;
        const unsigned short* fp = featB + (s << 6) + quad * 8;
        short8 a0 = *(const short8*)(fp);
        short8 a1 = *(const short8*)(fp + 32);
        #pragma unroll
        for (int tn = 0; tn < 4; ++tn) {
            floatx4 c = {0.f, 0.f, 0.f, 0.f};
            c = __builtin_amdgcn_mfma_f32_16x16x32_bf16(a0, bfr[tn][0], c, 0, 0, 0);
            c = __builtin_amdgcn_mfma_f32_16x16x32_bf16(a1, bfr[tn][1], c, 0, 0, 0);
            #pragma unroll
            for (int j = 0; j < 4; ++j)
                lds[w][(quad * 4 + j) * 68 + tn * 16 + l16] = c[j];
        }
        // lane l handles output row (l>>2), 16-col segment (l&3)
        int rowi = base + tm * 16 + rr;
        int p = (rowi < validEnd) ? pairS[rowi].y : -1;
        if (p >= 0) {
            const float* lp = &lds[w][rr * 68 + seg * 16];
            uint4 o0, o1;
            o0.x = pk2(lp[0],  lp[1]);  o0.y = pk2(lp[2],  lp[3]);
            o0.z = pk2(lp[4],  lp[5]);  o0.w = pk2(lp[6],  lp[7]);
            o1.x = pk2(lp[8],  lp[9]);  o1.y = pk2(lp[10], lp[11]);
            o1.z = pk2(lp[12], lp[13]); o1.w = pk2(lp[14], lp[15]);
            uint32_t* op = (uint32_t*)(msgE + (size_t)p * 64 + seg * 16);
            *(uint4*)(op)     = o0;
            *(uint4*)(op + 4) = o1;
        }
    }
}

// Phase B: one wave per dst node; msgE segments are contiguous (dst-sorted).
// 4 rows/iter: lane reads uint2 (4 cols) of row start+(lane>>4).
__global__ void __launch_bounds__(256)
k_reduce(const unsigned short* __restrict__ msgE,
         const int* __restrict__ dbase, float* __restrict__ out) {
    int n = blockIdx.x * 4 + (threadIdx.x >> 6);
    if (n >= NDN) return;
    int lane = threadIdx.x & 63;
    int end = dbase[n];                 // post-scatter: segment end
    int start = n ? dbase[n - 1] : 0;
    int c4 = (lane & 15) * 4;
    float ax = 0.f, ay = 0.f, az = 0.f, aw = 0.f;
    for (int row = start + (lane >> 4); row < end; row += 4) {
        uint2 v = *(const uint2*)(msgE + (size_t)row * 64 + c4);
        ax += bf2f(v.x & 0xffffu); ay += bf2f(v.x >> 16);
        az += bf2f(v.y & 0xffffu); aw += bf2f(v.y >> 16);
    }
    ax += __shfl_xor(ax, 16); ax += __shfl_xor(ax, 32);
    ay += __shfl_xor(ay, 16); ay += __shfl_xor(ay, 32);
    az += __shfl_xor(az, 16); az += __shfl_xor(az, 32);
    aw += __shfl_xor(aw, 16); aw += __shfl_xor(aw, 32);
    if (lane < 16) {
        float4 o = make_float4(ax, ay, az, aw);
        *(float4*)(out + (size_t)n * 64 + lane * 4) = o;
    }
}

// Fallback: atomic epilogue (proven R1 path), pairS = {src, dst}
__global__ void __launch_bounds__(256)
k_compute(const unsigned short* __restrict__ featB,
          const unsigned short* __restrict__ Wt,
          const int2* __restrict__ pairS, const int* __restrict__ Pve,
          float* __restrict__ out) {
    const int t = blockIdx.x * 4 + (threadIdx.x >> 6);
    const int base = t * 64;
    const int total = Pve[16];
    if (base >= total) return;
    int r = 0;
    while (base >= Pve[r + 1]) ++r;
    const int validEnd = Pve[17 + r];
    const int lane = threadIdx.x & 63;
    const int quad = lane >> 4;
    const int l16 = lane & 15;

    const unsigned short* wr = Wt + (r << 12);
    short8 bfr[4][2];
    #pragma unroll
    for (int tn = 0; tn < 4; ++tn)
        #pragma unroll
        for (int ks = 0; ks < 2; ++ks)
            bfr[tn][ks] = *(const short8*)(wr + ((tn * 16 + l16) << 6) + ks * 32 + quad * 8);

    #pragma unroll
    for (int tm = 0; tm < 4; ++tm) {
        int row = base + tm * 16 + l16;
        int s = (row < validEnd) ? pairS[row].x : 0;
        const unsigned short* fp = featB + (s << 6) + quad * 8;
        short8 a0 = *(const short8*)(fp);
        short8 a1 = *(const short8*)(fp + 32);
        floatx4 cc[4];
        #pragma unroll
        for (int tn = 0; tn < 4; ++tn) {
            floatx4 c = {0.f, 0.f, 0.f, 0.f};
            c = __builtin_amdgcn_mfma_f32_16x16x32_bf16(a0, bfr[tn][0], c, 0, 0, 0);
            c = __builtin_amdgcn_mfma_f32_16x16x32_bf16(a1, bfr[tn][1], c, 0, 0, 0);
            cc[tn] = c;
        }
        int pos0 = base + tm * 16 + quad * 4;
        #pragma unroll
        for (int j = 0; j < 4; ++j) {
            if (pos0 + j < validEnd) {
                int dn = pairS[pos0 + j].y;
                float* op = out + (dn << 6) + l16;
                #pragma unroll
                for (int tn = 0; tn < 4; ++tn)
                    atomicAdd(op + tn * 16, cc[tn][j]);
            }
        }
    }
}

extern "C" void kernel_launch(void* const* d_in, const int* in_sizes, int n_in,
                              void* d_out, int out_size, void* d_ws, size_t ws_size,
                              hipStream_t stream) {
    const float* feat = (const float*)d_in[0];
    const float* W    = (const float*)d_in[1];
    const int* src    = (const int*)d_in[2];
    const int* dst    = (const int*)d_in[3];
    const int* et     = (const int*)d_in[4];
    float* out = (float*)d_out;
    char* ws = (char*)d_ws;

    unsigned short* featB = (unsigned short*)(ws);
    unsigned short* Wt    = (unsigned short*)(ws + 12800000);
    int* hist  = (int*)(ws + 12931072);
    int* bbase = (int*)(ws + 12963840);
    int* Pve   = (int*)(ws + 12996608);
    int* dhist = (int*)(ws + 12996864);
    int* dbase = (int*)(ws + 13396992);
    int* csum  = (int*)(ws + 13797120);
    int2* pairS = (int2*)(ws + 13797632);
    unsigned short* msgE = (unsigned short*)(ws + 21805824);

    const int usePhases = (ws_size >= WS_NEED) ? 1 : 0;

    k_convert_feat<<<6250, 256, 0, stream>>>(feat, featB);
    k_convert_w<<<256, 256, 0, stream>>>(W, Wt);
    hipMemsetAsync(dhist, 0, NDN * sizeof(int), stream);
    k_hist<<<NB, 256, 0, stream>>>(et, dst, hist, dhist);
    k_scan<<<1, 1024, 0, stream>>>(hist, bbase, Pve);

    if (usePhases) {
        k_dscanA<<<NCHUNK, DCH, 0, stream>>>(dhist, dbase, csum);
        k_dscanB<<<NCHUNK, DCH, 0, stream>>>(dbase, csum);
        k_scatter<<<NB, 256, 0, stream>>>(et, src, dst, bbase, dbase, pairS, 1);
        k_computeA<<<(MAXTILES + 3) / 4, 256, 0, stream>>>(featB, Wt, pairS, Pve, msgE);
        k_reduce<<<(NDN + 3) / 4, 256, 0, stream>>>(msgE, dbase, out);
    } else {
        hipMemsetAsync(d_out, 0, (size_t)out_size * sizeof(float), stream);
        k_scatter<<<NB, 256, 0, stream>>>(et, src, dst, bbase, dbase, pairS, 0);
        k_compute<<<(MAXTILES + 3) / 4, 256, 0, stream>>>(featB, Wt, pairS, Pve, out);
    }
}

// Round 4
// 244.534 us; speedup vs baseline: 1.3631x; 1.1249x over previous
//
#include <hip/hip_runtime.h>
#include <hip/hip_bf16.h>
#include <stdint.h>

#define NNODES 100000
#define NEDGES 1000000
#define DIM 64
#define NRELS 16
#define EPB 2048
#define NB ((NEDGES + EPB - 1) / EPB)   /* 489 */
#define PADCAP (NEDGES + NRELS * 64)    /* 1001024 */
#define MAXTILES (PADCAP / 64)          /* 15641 */
#define NDN NNODES
#define DCH 1024
#define NCHUNK ((NDN + DCH - 1) / DCH)  /* 98 */

// ws layout (bytes):
//   featB  @ 0          : ushort[NNODES*64]   -> 12,800,000
//   Wt     @ 12800000   : ushort[16*64*64]    -> 12,931,072
//   hist   @ 12931072   : int[NB*16]          -> 12,963,840
//   bbase  @ 12963840   : int[NB*16]          -> 12,996,608
//   Pve    @ 12996608   : int[33]             -> 12,996,864
//   dhist  @ 12996864   : int[NDN]            -> 13,396,992
//   dbase  @ 13396992   : int[NDN]            -> 13,797,120  (EXCLUSIVE starts, immutable)
//   csum   @ 13797120   : int[NCHUNK]         -> 13,797,632
//   rank   @ 13797632   : ushort[NEDGES]      -> 15,797,632  (within-dst-segment rank)
//   pairS  @ 15797632   : int2[PADCAP]        -> 23,805,824  {src, dstpos|dst}
//   msgE   @ 23805824   : ushort[NEDGES*64]   -> 151,805,824
#define WS_NEED 151805824ull

using short8  = __attribute__((ext_vector_type(8))) short;
using floatx4 = __attribute__((ext_vector_type(4))) float;

__device__ __forceinline__ unsigned short f2bf(float f) {
    union { float f; uint32_t u; } v; v.f = f;
    uint32_t u = v.u;
    return (unsigned short)((u + 0x7FFFu + ((u >> 16) & 1u)) >> 16);
}
__device__ __forceinline__ float bf2f(uint32_t u16) {
    union { uint32_t u; float f; } v; v.u = u16 << 16;
    return v.f;
}
__device__ __forceinline__ uint32_t pk2(float a, float b) {
    __hip_bfloat162 h = __float22bfloat162_rn(make_float2(a, b));
    union { __hip_bfloat162 h; uint32_t u; } v; v.h = h;
    return v.u;
}

__global__ void k_convert_feat(const float* __restrict__ feat,
                               unsigned short* __restrict__ featB) {
    int i = (blockIdx.x * blockDim.x + threadIdx.x) * 4;
    const float4 f = *(const float4*)(feat + i);
    ushort4 o;
    o.x = f2bf(f.x); o.y = f2bf(f.y); o.z = f2bf(f.z); o.w = f2bf(f.w);
    *(ushort4*)(featB + i) = o;
}

// Wt[r][n][k] = bf16(W[r][k][n])
__global__ void k_convert_w(const float* __restrict__ W,
                            unsigned short* __restrict__ Wt) {
    int t = blockIdx.x * blockDim.x + threadIdx.x;
    int r = t >> 12, n = (t >> 6) & 63, k = t & 63;
    Wt[t] = f2bf(W[(r << 12) + (k << 6) + n]);
}

// fused: per-block relation hist + global dst hist; atomic return = segment rank
__global__ void k_hist(const int* __restrict__ et, const int* __restrict__ dst,
                       int* __restrict__ hist, int* __restrict__ dhist,
                       unsigned short* __restrict__ rank) {
    __shared__ int cnt[16];
    if (threadIdx.x < 16) cnt[threadIdx.x] = 0;
    __syncthreads();
    int start = blockIdx.x * EPB;
    int end = min(NEDGES, start + EPB);
    for (int i = start + threadIdx.x; i < end; i += 256) {
        atomicAdd(&cnt[et[i]], 1);
        rank[i] = (unsigned short)atomicAdd(&dhist[dst[i]], 1);
    }
    __syncthreads();
    if (threadIdx.x < 16) hist[blockIdx.x * 16 + threadIdx.x] = cnt[threadIdx.x];
}

__global__ void k_scan(const int* __restrict__ hist, int* __restrict__ bbase,
                       int* __restrict__ Pve) {
    __shared__ int s_cnt[16];
    __shared__ int s_P[17];
    int w = threadIdx.x >> 6;
    int lane = threadIdx.x & 63;
    int carry = 0;
    for (int c = 0; c < NB; c += 64) {
        int idx = c + lane;
        int v = (idx < NB) ? hist[idx * 16 + w] : 0;
        int x = v;
        #pragma unroll
        for (int off = 1; off < 64; off <<= 1) {
            int y = __shfl_up(x, off);
            if (lane >= off) x += y;
        }
        if (idx < NB) bbase[idx * 16 + w] = carry + x - v;
        carry += __shfl(x, 63);
    }
    if (lane == 0) s_cnt[w] = carry;
    __syncthreads();
    if (threadIdx.x == 0) {
        int p = 0;
        for (int r = 0; r < 16; ++r) {
            s_P[r] = p;
            Pve[r] = p;
            Pve[17 + r] = p + s_cnt[r];
            p += (s_cnt[r] + 63) & ~63;
        }
        s_P[16] = p;
        Pve[16] = p;
    }
    __syncthreads();
    int pw = s_P[w];
    for (int idx = lane; idx < NB; idx += 64)
        bbase[idx * 16 + w] += pw;
}

// per-chunk exclusive scan (1024/block) + chunk totals
__global__ void k_dscanA(const int* __restrict__ dhist, int* __restrict__ dbase,
                         int* __restrict__ csum) {
    __shared__ int wsum[16];
    __shared__ int woff[16];
    int t = threadIdx.x;
    int i = blockIdx.x * DCH + t;
    int v = (i < NDN) ? dhist[i] : 0;
    int lane = t & 63, wv = t >> 6;
    int x = v;
    #pragma unroll
    for (int off = 1; off < 64; off <<= 1) {
        int y = __shfl_up(x, off);
        if (lane >= off) x += y;
    }
    if (lane == 63) wsum[wv] = x;
    __syncthreads();
    if (wv == 0) {
        int s = (lane < 16) ? wsum[lane] : 0;
        #pragma unroll
        for (int off = 1; off < 16; off <<= 1) {
            int y = __shfl_up(s, off);
            if (lane >= off) s += y;
        }
        if (lane < 16) woff[lane] = s - wsum[lane];
        if (lane == 15) csum[blockIdx.x] = s;
    }
    __syncthreads();
    if (i < NDN) dbase[i] = woff[wv] + x - v;
}

__global__ void k_dscanB(int* __restrict__ dbase, const int* __restrict__ csum) {
    __shared__ int soff;
    int b = blockIdx.x, t = threadIdx.x;
    if (t < 64) {
        int s = ((t < b) ? csum[t] : 0) + ((t + 64 < b) ? csum[t + 64] : 0);
        #pragma unroll
        for (int off = 32; off >= 1; off >>= 1) s += __shfl_down(s, off);
        if (t == 0) soff = s;
    }
    __syncthreads();
    int i = b * DCH + t;
    if (i < NDN) dbase[i] += soff;
}

// pairS[pos] = {src, dstpos} (phases) or {src, dst} (fallback).
// dstpos = dbase[dst] + rank  — plain cached read, NO atomic.
__global__ void k_scatter(const int* __restrict__ et, const int* __restrict__ src,
                          const int* __restrict__ dst, const int* __restrict__ bbase,
                          const int* __restrict__ dbase,
                          const unsigned short* __restrict__ rank,
                          int2* __restrict__ pairS, int buildPos) {
    __shared__ int base[16];
    if (threadIdx.x < 16) base[threadIdx.x] = bbase[blockIdx.x * 16 + threadIdx.x];
    __syncthreads();
    int start = blockIdx.x * EPB;
    int end = min(NEDGES, start + EPB);
    for (int i = start + threadIdx.x; i < end; i += 256) {
        int r = et[i];
        int pos = atomicAdd(&base[r], 1);
        int d = dst[i];
        int second = buildPos ? (dbase[d] + (int)rank[i]) : d;
        pairS[pos] = make_int2(src[i], second);
    }
}

// Phase A: per 64-edge tile (single relation), GEMM -> bf16 msg row at dstpos
__global__ void __launch_bounds__(256)
k_computeA(const unsigned short* __restrict__ featB,
           const unsigned short* __restrict__ Wt,
           const int2* __restrict__ pairS, const int* __restrict__ Pve,
           unsigned short* __restrict__ msgE) {
    __shared__ float lds[4][16 * 68];   // per-wave 16x64 transpose, stride 68
    const int w = threadIdx.x >> 6;
    const int t = blockIdx.x * 4 + w;
    const int base = t * 64;
    const int total = Pve[16];
    if (base >= total) return;
    int r = 0;
    while (base >= Pve[r + 1]) ++r;
    const int validEnd = Pve[17 + r];
    const int lane = threadIdx.x & 63;
    const int quad = lane >> 4;
    const int l16 = lane & 15;

    const unsigned short* wr = Wt + (r << 12);
    short8 bfr[4][2];
    #pragma unroll
    for (int tn = 0; tn < 4; ++tn)
        #pragma unroll
        for (int ks = 0; ks < 2; ++ks)
            bfr[tn][ks] = *(const short8*)(wr + ((tn * 16 + l16) << 6) + ks * 32 + quad * 8);

    const int rr = lane >> 2, seg = lane & 3;
    #pragma unroll
    for (int tm = 0; tm < 4; ++tm) {
        int row = base + tm * 16 + l16;
        int s = (row < validEnd) ? pairS[row].x : 0;
        const unsigned short* fp = featB + (s << 6) + quad * 8;
        short8 a0 = *(const short8*)(fp);
        short8 a1 = *(const short8*)(fp + 32);
        #pragma unroll
        for (int tn = 0; tn < 4; ++tn) {
            floatx4 c = {0.f, 0.f, 0.f, 0.f};
            c = __builtin_amdgcn_mfma_f32_16x16x32_bf16(a0, bfr[tn][0], c, 0, 0, 0);
            c = __builtin_amdgcn_mfma_f32_16x16x32_bf16(a1, bfr[tn][1], c, 0, 0, 0);
            #pragma unroll
            for (int j = 0; j < 4; ++j)
                lds[w][(quad * 4 + j) * 68 + tn * 16 + l16] = c[j];
        }
        // lane l handles output row (l>>2), 16-col segment (l&3)
        int rowi = base + tm * 16 + rr;
        int p = (rowi < validEnd) ? pairS[rowi].y : -1;
        if (p >= 0) {
            const float* lp = &lds[w][rr * 68 + seg * 16];
            uint4 o0, o1;
            o0.x = pk2(lp[0],  lp[1]);  o0.y = pk2(lp[2],  lp[3]);
            o0.z = pk2(lp[4],  lp[5]);  o0.w = pk2(lp[6],  lp[7]);
            o1.x = pk2(lp[8],  lp[9]);  o1.y = pk2(lp[10], lp[11]);
            o1.z = pk2(lp[12], lp[13]); o1.w = pk2(lp[14], lp[15]);
            uint32_t* op = (uint32_t*)(msgE + (size_t)p * 64 + seg * 16);
            *(uint4*)(op)     = o0;
            *(uint4*)(op + 4) = o1;
        }
    }
}

// Phase B: one wave per dst node; msgE segments contiguous (dst-sorted).
// 4 rows/iter: lane reads uint2 (4 cols) of row start+(lane>>4).
__global__ void __launch_bounds__(256)
k_reduce(const unsigned short* __restrict__ msgE,
         const int* __restrict__ dbase, float* __restrict__ out) {
    int n = blockIdx.x * 4 + (threadIdx.x >> 6);
    if (n >= NDN) return;
    int lane = threadIdx.x & 63;
    int start = dbase[n];
    int end = (n + 1 < NDN) ? dbase[n + 1] : NEDGES;
    int c4 = (lane & 15) * 4;
    float ax = 0.f, ay = 0.f, az = 0.f, aw = 0.f;
    for (int row = start + (lane >> 4); row < end; row += 4) {
        uint2 v = *(const uint2*)(msgE + (size_t)row * 64 + c4);
        ax += bf2f(v.x & 0xffffu); ay += bf2f(v.x >> 16);
        az += bf2f(v.y & 0xffffu); aw += bf2f(v.y >> 16);
    }
    ax += __shfl_xor(ax, 16); ax += __shfl_xor(ax, 32);
    ay += __shfl_xor(ay, 16); ay += __shfl_xor(ay, 32);
    az += __shfl_xor(az, 16); az += __shfl_xor(az, 32);
    aw += __shfl_xor(aw, 16); aw += __shfl_xor(aw, 32);
    if (lane < 16) {
        float4 o = make_float4(ax, ay, az, aw);
        *(float4*)(out + (size_t)n * 64 + lane * 4) = o;
    }
}

// Fallback: atomic epilogue (proven R1 path), pairS = {src, dst}
__global__ void __launch_bounds__(256)
k_compute(const unsigned short* __restrict__ featB,
          const unsigned short* __restrict__ Wt,
          const int2* __restrict__ pairS, const int* __restrict__ Pve,
          float* __restrict__ out) {
    const int t = blockIdx.x * 4 + (threadIdx.x >> 6);
    const int base = t * 64;
    const int total = Pve[16];
    if (base >= total) return;
    int r = 0;
    while (base >= Pve[r + 1]) ++r;
    const int validEnd = Pve[17 + r];
    const int lane = threadIdx.x & 63;
    const int quad = lane >> 4;
    const int l16 = lane & 15;

    const unsigned short* wr = Wt + (r << 12);
    short8 bfr[4][2];
    #pragma unroll
    for (int tn = 0; tn < 4; ++tn)
        #pragma unroll
        for (int ks = 0; ks < 2; ++ks)
            bfr[tn][ks] = *(const short8*)(wr + ((tn * 16 + l16) << 6) + ks * 32 + quad * 8);

    #pragma unroll
    for (int tm = 0; tm < 4; ++tm) {
        int row = base + tm * 16 + l16;
        int s = (row < validEnd) ? pairS[row].x : 0;
        const unsigned short* fp = featB + (s << 6) + quad * 8;
        short8 a0 = *(const short8*)(fp);
        short8 a1 = *(const short8*)(fp + 32);
        floatx4 cc[4];
        #pragma unroll
        for (int tn = 0; tn < 4; ++tn) {
            floatx4 c = {0.f, 0.f, 0.f, 0.f};
            c = __builtin_amdgcn_mfma_f32_16x16x32_bf16(a0, bfr[tn][0], c, 0, 0, 0);
            c = __builtin_amdgcn_mfma_f32_16x16x32_bf16(a1, bfr[tn][1], c, 0, 0, 0);
            cc[tn] = c;
        }
        int pos0 = base + tm * 16 + quad * 4;
        #pragma unroll
        for (int j = 0; j < 4; ++j) {
            if (pos0 + j < validEnd) {
                int dn = pairS[pos0 + j].y;
                float* op = out + (dn << 6) + l16;
                #pragma unroll
                for (int tn = 0; tn < 4; ++tn)
                    atomicAdd(op + tn * 16, cc[tn][j]);
            }
        }
    }
}

extern "C" void kernel_launch(void* const* d_in, const int* in_sizes, int n_in,
                              void* d_out, int out_size, void* d_ws, size_t ws_size,
                              hipStream_t stream) {
    const float* feat = (const float*)d_in[0];
    const float* W    = (const float*)d_in[1];
    const int* src    = (const int*)d_in[2];
    const int* dst    = (const int*)d_in[3];
    const int* et     = (const int*)d_in[4];
    float* out = (float*)d_out;
    char* ws = (char*)d_ws;

    unsigned short* featB = (unsigned short*)(ws);
    unsigned short* Wt    = (unsigned short*)(ws + 12800000);
    int* hist  = (int*)(ws + 12931072);
    int* bbase = (int*)(ws + 12963840);
    int* Pve   = (int*)(ws + 12996608);
    int* dhist = (int*)(ws + 12996864);
    int* dbase = (int*)(ws + 13396992);
    int* csum  = (int*)(ws + 13797120);
    unsigned short* rank = (unsigned short*)(ws + 13797632);
    int2* pairS = (int2*)(ws + 15797632);
    unsigned short* msgE = (unsigned short*)(ws + 23805824);

    const int usePhases = (ws_size >= WS_NEED) ? 1 : 0;

    k_convert_feat<<<6250, 256, 0, stream>>>(feat, featB);
    k_convert_w<<<256, 256, 0, stream>>>(W, Wt);
    hipMemsetAsync(dhist, 0, NDN * sizeof(int), stream);
    k_hist<<<NB, 256, 0, stream>>>(et, dst, hist, dhist, rank);
    k_scan<<<1, 1024, 0, stream>>>(hist, bbase, Pve);

    if (usePhases) {
        k_dscanA<<<NCHUNK, DCH, 0, stream>>>(dhist, dbase, csum);
        k_dscanB<<<NCHUNK, DCH, 0, stream>>>(dbase, csum);
        k_scatter<<<NB, 256, 0, stream>>>(et, src, dst, bbase, dbase, rank, pairS, 1);
        k_computeA<<<(MAXTILES + 3) / 4, 256, 0, stream>>>(featB, Wt, pairS, Pve, msgE);
        k_reduce<<<(NDN + 3) / 4, 256, 0, stream>>>(msgE, dbase, out);
    } else {
        hipMemsetAsync(d_out, 0, (size_t)out_size * sizeof(float), stream);
        k_scatter<<<NB, 256, 0, stream>>>(et, src, dst, bbase, dbase, rank, pairS, 0);
        k_compute<<<(MAXTILES + 3) / 4, 256, 0, stream>>>(featB, Wt, pairS, Pve, out);
    }
}